// Round 19
// baseline (1536.028 us; speedup 1.0000x reference)
//
#include <hip/hip_runtime.h>
#include <stdint.h>

typedef unsigned short u16;
typedef __attribute__((ext_vector_type(8))) short short8;
typedef __attribute__((ext_vector_type(4))) float f32x4;

#define DEVI __device__ __forceinline__

static constexpr int TT = 768;
static constexpr int CC = 2048;
static constexpr int MM = 3072;
static constexpr int HH = 32;

DEVI float b2f(u16 u){ union{float f; unsigned int i;} x; x.i = ((unsigned int)u)<<16; return x.f; }
DEVI float b2fs(short s){ return b2f((u16)s); }
DEVI u16 f2b(float f){
  unsigned int u = __builtin_bit_cast(unsigned int, f);
  unsigned int r = (u + 0x7fffu + ((u>>16)&1u)) >> 16;
  return (u16)r;
}

DEVI void gload16(const void* g, void* s){
  __builtin_amdgcn_global_load_lds((const __attribute__((address_space(1))) void*)g,
                                   (__attribute__((address_space(3))) void*)s, 16, 0, 0);
}

// all-reduce over 8 consecutive lanes, pure DPP + half-mirror
DEVI float rdx8(float x){
  int xi = __builtin_bit_cast(int, x);
  x += __builtin_bit_cast(float, __builtin_amdgcn_update_dpp(0, xi, 0xB1, 0xF, 0xF, true));
  xi = __builtin_bit_cast(int, x);
  x += __builtin_bit_cast(float, __builtin_amdgcn_update_dpp(0, xi, 0x4E, 0xF, 0xF, true));
  xi = __builtin_bit_cast(int, x);
  x += __builtin_bit_cast(float, __builtin_amdgcn_update_dpp(0, xi, 0x141, 0xF, 0xF, true));
  return x;
}

__global__ __launch_bounds__(256) void k_fillf(float* __restrict__ out, float v, int n){
  for (int i = blockIdx.x*256 + threadIdx.x; i < n; i += gridDim.x*256) out[i] = v;
}

__global__ void k_tpose(const float* __restrict__ src, int R, int Cn, u16* __restrict__ dst, int ldd){
  __shared__ float tile[32][33];
  int c0 = blockIdx.x*32, r0 = blockIdx.y*32;
  #pragma unroll
  for (int i=0;i<4;++i){
    int r = r0 + threadIdx.y + i*8, c = c0 + threadIdx.x;
    tile[threadIdx.y + i*8][threadIdx.x] = (r<R && c<Cn) ? src[(size_t)r*Cn + c] : 0.f;
  }
  __syncthreads();
  #pragma unroll
  for (int i=0;i<4;++i){
    int c = c0 + threadIdx.y + i*8, r = r0 + threadIdx.x;
    if (c<Cn && r<R) dst[(size_t)c*ldd + r] = f2b(tile[threadIdx.x][threadIdx.y + i*8]);
  }
}

__global__ __launch_bounds__(256) void k_lnb(const float* __restrict__ in, const float* __restrict__ w,
                                             const float* __restrict__ bias, u16* __restrict__ out){
  __shared__ float red[8];
  int m = blockIdx.x;
  const float* x = in + (size_t)m*CC;
  float v[8]; float s=0.f, ss=0.f;
  #pragma unroll
  for (int i=0;i<8;++i){ v[i] = x[threadIdx.x + i*256]; s += v[i]; ss += v[i]*v[i]; }
  #pragma unroll
  for (int o=32;o;o>>=1){ s += __shfl_xor(s,o); ss += __shfl_xor(ss,o); }
  int wid = threadIdx.x>>6;
  if ((threadIdx.x&63)==0){ red[wid]=s; red[4+wid]=ss; }
  __syncthreads();
  s  = red[0]+red[1]+red[2]+red[3];
  ss = red[4]+red[5]+red[6]+red[7];
  float mean = s*(1.f/2048.f);
  float var  = ss*(1.f/2048.f) - mean*mean;
  float rstd = rsqrtf(fmaxf(var,0.f) + 1e-5f);
  #pragma unroll
  for (int i=0;i<8;++i){
    int c = threadIdx.x + i*256;
    out[(size_t)m*CC + c] = f2b((v[i]-mean)*rstd*w[c] + bias[c]);
  }
}

__global__ __launch_bounds__(256) void k_mixA(const u16* __restrict__ xn,
  const float* __restrict__ cw, const float* __restrict__ ca, const float* __restrict__ cv,
  const float* __restrict__ cg,
  u16* __restrict__ ow, u16* __restrict__ oa, u16* __restrict__ ov, u16* __restrict__ og)
{
  int m = blockIdx.x; int t = m % TT;
  const u16* cur = xn + (size_t)m*CC;
  const u16* prv = cur - CC;
  bool has = (t>0);
  #pragma unroll
  for (int i=0;i<8;++i){
    int c = threadIdx.x + i*256;
    float xc = b2f(cur[c]);
    float xx = (has ? b2f(prv[c]) : 0.f) - xc;
    size_t o = (size_t)m*CC + c;
    ow[o]=f2b(xc + xx*cw[c]); oa[o]=f2b(xc + xx*ca[c]);
    ov[o]=f2b(xc + xx*cv[c]); og[o]=f2b(xc + xx*cg[c]);
  }
}

__global__ __launch_bounds__(256) void k_mixB(const u16* __restrict__ xn,
  const float* __restrict__ cr, const float* __restrict__ ck,
  u16* __restrict__ orr, u16* __restrict__ ok)
{
  int m = blockIdx.x; int t = m % TT;
  const u16* cur = xn + (size_t)m*CC;
  const u16* prv = cur - CC;
  bool has = (t>0);
  #pragma unroll
  for (int i=0;i<8;++i){
    int c = threadIdx.x + i*256;
    float xc = b2f(cur[c]);
    float xx = (has ? b2f(prv[c]) : 0.f) - xc;
    size_t o = (size_t)m*CC + c;
    orr[o]=f2b(xc + xx*cr[c]); ok[o]=f2b(xc + xx*ck[c]);
  }
}

__global__ __launch_bounds__(256) void k_mix1(const u16* __restrict__ xn, const float* __restrict__ cf,
                                              u16* __restrict__ out){
  int m = blockIdx.x; int t = m % TT;
  const u16* cur = xn + (size_t)m*CC;
  const u16* prv = cur - CC;
  bool has = (t>0);
  #pragma unroll
  for (int i=0;i<8;++i){
    int c = threadIdx.x + i*256;
    float xc = b2f(cur[c]);
    float xx = (has ? b2f(prv[c]) : 0.f) - xc;
    out[(size_t)m*CC + c] = f2b(xc + xx*cf[c]);
  }
}

// ---------------- small-N bf16 MFMA GEMM: 128x128 tile (proven r13-r18 skeleton)
__global__ __launch_bounds__(256,3) void k_gemm(
    const u16* A0, const u16* A1, const u16* A2,
    int amode, int lda,
    const u16* __restrict__ BT, int ldb,
    void* C0, void* C1, void* C2, int ldc, int K,
    int emode, const float* __restrict__ aux)
{
  const int tid = threadIdx.x;
  const int w = tid>>6, l = tid&63;

  const int NT = gridDim.x;
  const int nwg = NT * gridDim.y;
  int bid = blockIdx.y * NT + blockIdx.x;
  int qq = nwg >> 3, rr = nwg & 7;
  int xcd = bid & 7, pos = bid >> 3;
  int nid = (xcd < rr ? xcd*(qq+1) : rr*(qq+1) + (xcd-rr)*qq) + pos;
  const int ntile = nid % NT;
  const int mtile = nid / NT;

  const u16* A = A0;
  if (amode==1){ A = (ntile==0)?A0:(ntile==1)?A1:A2; }
  else if (amode==2){ int g = ntile>>4; A = (g==0)?A0:(g==1)?A1:A2; }

  __shared__ __align__(16) u16 As[3*4096];
  __shared__ __align__(16) u16 Bs[3*4096];

  const int sr = w*16 + (l>>2);
  const int sk = (((l&3) ^ ((l>>2)&3)))*8;
  const u16* Ag = A  + (size_t)(mtile*128 + sr)*lda + sk;
  const u16* Bg = BT + (size_t)(ntile*128 + sr)*ldb + sk;
  const size_t a64 = (size_t)64*lda, b64 = (size_t)64*ldb;
  const int wo = w*512;

  const int wm = w>>1, wn = w&1;
  const int fr = l&15;
  const int fq = ((l>>4) ^ (fr&3))*8;
  const int aoff = (wm*64 + fr)*32 + fq;
  const int boff = (wn*64 + fr)*32 + fq;

  f32x4 acc[4][4];
  const f32x4 zz = {0.f,0.f,0.f,0.f};
  #pragma unroll
  for (int mi=0;mi<4;++mi)
    #pragma unroll
    for (int ni=0;ni<4;++ni) acc[mi][ni] = zz;

  const int nt = K >> 5;

#define STAGE(bufi, k0) do{ \
    u16* dA = As + (bufi)*4096 + wo; \
    u16* dB = Bs + (bufi)*4096 + wo; \
    gload16(Ag + (k0),        dA); \
    gload16(Ag + a64 + (k0),  dA + 2048); \
    gload16(Bg + (k0),        dB); \
    gload16(Bg + b64 + (k0),  dB + 2048); \
  }while(0)

  STAGE(0, 0);
  if (nt > 1) STAGE(1, 32);

  int cur = 0;
  for (int t=0; t<nt; ++t){
    if (t == nt-1){ asm volatile("s_waitcnt vmcnt(0)" ::: "memory"); }
    else          { asm volatile("s_waitcnt vmcnt(4)" ::: "memory"); }
    __builtin_amdgcn_s_barrier();
    if (t+2 < nt){
      int nb = cur+2; if (nb>=3) nb-=3;
      STAGE(nb, (t+2)<<5);
    }
    const u16* Ab = As + cur*4096;
    const u16* Bb = Bs + cur*4096;
    short8 af[4], bfr[4];
    #pragma unroll
    for (int mi=0;mi<4;++mi) af[mi]  = *(const short8*)(Ab + aoff + mi*512);
    #pragma unroll
    for (int ni=0;ni<4;++ni) bfr[ni] = *(const short8*)(Bb + boff + ni*512);
    #pragma unroll
    for (int mi=0;mi<4;++mi)
      #pragma unroll
      for (int ni=0;ni<4;++ni)
        acc[mi][ni] = __builtin_amdgcn_mfma_f32_16x16x32_bf16(af[mi], bfr[ni], acc[mi][ni], 0,0,0);
    cur = (cur+1==3)?0:cur+1;
  }
#undef STAGE

  const int rb0 = mtile*128 + wm*64 + (l>>4)*4;
  const int cb0 = ntile*128 + wn*64 + fr;
  #pragma unroll
  for (int mi=0;mi<4;++mi){
    #pragma unroll
    for (int ni=0;ni<4;++ni){
      #pragma unroll
      for (int q2=0;q2<4;++q2){
        int row = rb0 + mi*16 + q2;
        int col = cb0 + ni*16;
        float v = acc[mi][ni][q2];
        if (emode==0){
          ((float*)C0)[(size_t)row*ldc + col] = v;
        } else if (emode==1){
          float valw = aux[col] + v;
          float zneg = -valw;
          float sp = (zneg > 20.f) ? zneg : log1pf(expf(zneg));
          float wlog = -sp - 0.5f;
          float dec = expf(-expf(wlog));
          int b_ = row/TT, t_ = row - b_*TT;
          int h_ = col>>6, n_ = col&63;
          ((float*)C0)[((size_t)(b_*HH + h_)*TT + t_)*64 + n_] = dec;
        } else if (emode==2){
          float s = 1.f/(1.f+expf(-(aux[col]+v)));
          ((u16*)C0)[(size_t)row*ldc + col] = f2b(s);
        } else if (emode==3){
          ((float*)C0)[(size_t)row*ldc + col] = aux[(size_t)row*ldc + col] + v;
        } else if (emode==4){
          float r_ = fmaxf(v, 0.f);
          ((u16*)C0)[(size_t)row*ldc + col] = f2b(r_*r_);
        } else if (emode==5){
          ((u16*)C0)[(size_t)row*ldc + col] = f2b(aux[(size_t)row*ldc + col] + v);
        } else if (emode==6){
          ((u16*)C0)[(size_t)row*ldc + col] = f2b(v);
        } else if (emode==7){
          float r_ = v;
          if (col < 128) r_ = tanhf(v);
          else if (col >= 384) r_ = 1.f/(1.f+expf(-v));
          ((u16*)C0)[(size_t)row*ldc + col] = f2b(r_);
        } else if (emode==8){
          int b_ = row/TT, t_ = row - b_*TT;
          int h_ = col>>6, n_ = col&63;
          ((u16*)C0)[((size_t)(b_*HH + h_)*TT + t_)*64 + n_] = f2b(v);
        } else if (emode==9){
          float s = 1.f/(1.f+expf(-(aux[col]+v)));
          int b_ = row/TT, t_ = row - b_*TT;
          int h_ = col>>6, n_ = col&63;
          ((u16*)C0)[((size_t)(b_*HH + h_)*TT + t_)*64 + n_] = f2b(s);
        } else if (emode==10){
          int g = col>>11, c2 = col&2047;
          int b_ = row/TT, t_ = row - b_*TT;
          int h_ = c2>>6, n_ = c2&63;
          u16* dst = (g==0)?(u16*)C0:(g==1)?(u16*)C1:(u16*)C2;
          dst[((size_t)(b_*HH + h_)*TT + t_)*64 + n_] = f2b(v);
        } else { // 11
          float s = 1.f/(1.f+expf(-v));
          ((u16*)C0)[(size_t)row*ldc + (col+384)] = f2b(s);
        }
      }
    }
  }
}

// ---------------- big-tile GEMM: 256x128 block, 4 waves of 128x64 (acc 8x4),
// FLOP/LDS-byte +33% vs 128x128. Tri-buffered, counted vmcnt(6), XCD swizzle.
// emodes: 0 f32 | 3 aux+v f32 | 4 relu^2 bf16 | 10 rkv scatter
__global__ __launch_bounds__(256,2) void k_gemm2(
    const u16* A0, const u16* A1, const u16* A2,
    int amode, int lda,
    const u16* __restrict__ BT, int ldb,
    void* C0, void* C1, void* C2, int ldc, int K,
    int emode, const float* __restrict__ aux)
{
  const int tid = threadIdx.x;
  const int w = tid>>6, l = tid&63;

  const int NT = gridDim.x;
  const int nwg = NT * gridDim.y;
  int bid = blockIdx.y * NT + blockIdx.x;
  int qq = nwg >> 3, rr = nwg & 7;
  int xcd = bid & 7, pos = bid >> 3;
  int nid = (xcd < rr ? xcd*(qq+1) : rr*(qq+1) + (xcd-rr)*qq) + pos;
  const int ntile = nid % NT;
  const int mtile = nid / NT;

  const u16* A = A0;
  if (amode==2){ int g = ntile>>4; A = (g==0)?A0:(g==1)?A1:A2; }

  __shared__ __align__(16) u16 As[3*8192];   // 256x32 per buffer (16KB)
  __shared__ __align__(16) u16 Bs[3*4096];   // 128x32 per buffer (8KB)

  const int sr4 = l>>2;                       // 0..15
  const int skb = ((l&3) ^ (sr4&3))*8;        // pre-swizzled source col-block
  const u16* Ag = A  + (size_t)(mtile*256 + w*64 + sr4)*lda + skb;
  const u16* Bg = BT + (size_t)(ntile*128 + w*32 + sr4)*ldb + skb;
  const size_t l16a = (size_t)16*lda, l16b = (size_t)16*ldb;

  const int wm = w>>1, wn = w&1;
  const int fr = l&15;
  const int fq = ((l>>4) ^ (fr&3))*8;
  const int aoff = (wm*128 + fr)*32 + fq;
  const int boff = (wn*64 + fr)*32 + fq;

  f32x4 acc[8][4];
  const f32x4 zz = {0.f,0.f,0.f,0.f};
  #pragma unroll
  for (int mi=0;mi<8;++mi)
    #pragma unroll
    for (int ni=0;ni<4;++ni) acc[mi][ni] = zz;

  const int nt = K >> 5;

#define STAGE2(bufi, k0) do{ \
    u16* dA = As + (bufi)*8192 + w*2048; \
    u16* dB = Bs + (bufi)*4096 + w*1024; \
    gload16(Ag + (k0),          dA); \
    gload16(Ag + l16a + (k0),   dA + 512); \
    gload16(Ag + 2*l16a + (k0), dA + 1024); \
    gload16(Ag + 3*l16a + (k0), dA + 1536); \
    gload16(Bg + (k0),          dB); \
    gload16(Bg + l16b + (k0),   dB + 512); \
  }while(0)

  STAGE2(0, 0);
  if (nt > 1) STAGE2(1, 32);

  int cur = 0;
  for (int t=0; t<nt; ++t){
    if (t == nt-1){ asm volatile("s_waitcnt vmcnt(0)" ::: "memory"); }
    else          { asm volatile("s_waitcnt vmcnt(6)" ::: "memory"); }
    __builtin_amdgcn_s_barrier();
    if (t+2 < nt){
      int nb = cur+2; if (nb>=3) nb-=3;
      STAGE2(nb, (t+2)<<5);
    }
    const u16* Ab = As + cur*8192;
    const u16* Bb = Bs + cur*4096;
    short8 af[8], bfr[4];
    #pragma unroll
    for (int mi=0;mi<8;++mi) af[mi]  = *(const short8*)(Ab + aoff + mi*512);
    #pragma unroll
    for (int ni=0;ni<4;++ni) bfr[ni] = *(const short8*)(Bb + boff + ni*512);
    #pragma unroll
    for (int mi=0;mi<8;++mi)
      #pragma unroll
      for (int ni=0;ni<4;++ni)
        acc[mi][ni] = __builtin_amdgcn_mfma_f32_16x16x32_bf16(af[mi], bfr[ni], acc[mi][ni], 0,0,0);
    cur = (cur+1==3)?0:cur+1;
  }
#undef STAGE2

  const int rb0 = mtile*256 + wm*128 + (l>>4)*4;
  const int cb0 = ntile*128 + wn*64 + fr;
  #pragma unroll
  for (int mi=0;mi<8;++mi){
    #pragma unroll
    for (int ni=0;ni<4;++ni){
      #pragma unroll
      for (int q2=0;q2<4;++q2){
        int row = rb0 + mi*16 + q2;
        int col = cb0 + ni*16;
        float v = acc[mi][ni][q2];
        if (emode==0){
          ((float*)C0)[(size_t)row*ldc + col] = v;
        } else if (emode==3){
          ((float*)C0)[(size_t)row*ldc + col] = aux[(size_t)row*ldc + col] + v;
        } else if (emode==4){
          float r_ = fmaxf(v, 0.f);
          ((u16*)C0)[(size_t)row*ldc + col] = f2b(r_*r_);
        } else { // 10: rkv scatter
          int g = col>>11, c2 = col&2047;
          int b_ = row/TT, t_ = row - b_*TT;
          int h_ = c2>>6, n_ = c2&63;
          u16* dst = (g==0)?(u16*)C0:(g==1)?(u16*)C1:(u16*)C2;
          dst[((size_t)(b_*HH + h_)*TT + t_)*64 + n_] = f2b(v);
        }
      }
    }
  }
}

// ---------------- rec prep: k,v in place; a,b to f32 buffers
__global__ __launch_bounds__(256) void k_make_rec3(
  u16* __restrict__ ksc, u16* __restrict__ vsc,
  const u16* __restrict__ asc, const u16* __restrict__ gsc,
  float* __restrict__ af, float* __restrict__ bf,
  const float* __restrict__ v_first, const float* __restrict__ k_k, const float* __restrict__ k_a)
{
  int idx = blockIdx.x*4 + (threadIdx.x>>6);
  int l = threadIdx.x & 63;
  int bh = idx / TT, t = idx - bh*TT;
  int b = bh >> 5, h = bh & 31;
  int c = h*64 + l;
  size_t off = (size_t)idx*64 + l;
  size_t mo = ((size_t)b*TT + t)*CC + c;
  float kq = b2f(ksc[off]);
  float vv = b2f(vsc[off]);
  float aa = b2f(asc[off]);
  float sg = b2f(gsc[off]);
  float vf = v_first[mo];
  float kkr = kq * k_k[c];
  float s2 = kkr*kkr;
  #pragma unroll
  for (int o=32;o;o>>=1) s2 += __shfl_xor(s2,o);
  float kk = kkr / fmaxf(sqrtf(s2), 1e-12f);
  ksc[off] = f2b(kq*(1.f + (aa-1.f)*k_a[c]));
  vsc[off] = f2b(vv + (vf-vv)*sg);
  af[off] = -kk;
  bf[off] = kk*aa;
}

// ---------------- RWKV7 recurrence (r17/r18 proven)
static constexpr int RCH = 16;
static constexpr int RNC = TT / RCH;
static constexpr int RBUF = 18432;

__global__ __launch_bounds__(256,1) void k_rwkv(
    const float* __restrict__ decay, const float* __restrict__ af, const float* __restrict__ bf,
    const u16* __restrict__ rb, const u16* __restrict__ kb, const u16* __restrict__ vb,
    u16* __restrict__ y)
{
  __shared__ __align__(16) char lds[3*RBUF];
  int blk = blockIdx.x;
  int bh = blk >> 1, half = blk & 1;
  int b = bh>>5, h = bh&31;
  int tid = threadIdx.x, w = tid>>6, l = tid&63;
  const int row = half*32 + w*8 + (l>>3);
  const int g = l&7;
  const int j0 = g*8;
  const size_t base = (size_t)bh * (TT*64);

  const float* dB = decay + base;
  const float* aB = af + base;
  const float* bB = bf + base;
  const u16*  rB = rb + base;
  const u16*  kB = kb + base;
  const u16*  vB = vb + base;

  float S[8];
  #pragma unroll
  for (int q=0;q<8;++q) S[q]=0.f;
  float ycur[RCH], yprev[RCH];
  size_t yb = (size_t)b*TT*CC + h*64 + row;

#define RSTAGE(bufi, c) do{ \
    char* bs = lds + (bufi)*RBUF; \
    size_t cf = (size_t)(c)*1024; \
    gload16(dB + cf + tid*4, bs + tid*16); \
    gload16(aB + cf + tid*4, bs + 4096 + tid*16); \
    gload16(bB + cf + tid*4, bs + 8192 + tid*16); \
    if (l < 32){ \
      int eo = w*256 + l*8; int bo = w*512 + l*16; \
      gload16(rB + cf + eo, bs + 12288 + bo); \
      gload16(kB + cf + eo, bs + 14336 + bo); \
      gload16(vB + cf + eo, bs + 16384 + bo); \
    } \
  }while(0)

  RSTAGE(0, 0);
  RSTAGE(1, 1);

  int cur = 0;
  for (int c=0; c<RNC; ++c){
    if (c == RNC-1){ asm volatile("s_waitcnt vmcnt(0)" ::: "memory"); }
    else           { asm volatile("s_waitcnt vmcnt(6)" ::: "memory"); }
    __builtin_amdgcn_s_barrier();
    if (c > 0){
      int t0 = (c-1)*RCH;
      #pragma unroll
      for (int s=0;s<RCH;++s) if (g==0) y[yb + (size_t)(t0+s)*CC] = f2b(yprev[s]);
    }
    asm volatile("" ::: "memory");
    if (c+2 < RNC){
      int nb = cur+2; if (nb>=3) nb-=3;
      RSTAGE(nb, c+2);
    }
    asm volatile("" ::: "memory");
    const char* bs = lds + cur*RBUF;
    #pragma unroll
    for (int s=0;s<RCH;++s){
      const f32x4* aV = (const f32x4*)(bs + 4096 + s*256 + j0*4);
      f32x4 a0v = aV[0], a1v = aV[1];
      float sa = ((S[0]*a0v[0] + S[1]*a0v[1]) + (S[2]*a0v[2] + S[3]*a0v[3]))
               + ((S[4]*a1v[0] + S[5]*a1v[1]) + (S[6]*a1v[2] + S[7]*a1v[3]));
      sa = rdx8(sa);
      const f32x4* dV = (const f32x4*)(bs + s*256 + j0*4);
      const f32x4* bV = (const f32x4*)(bs + 8192 + s*256 + j0*4);
      f32x4 d0v = dV[0], d1v = dV[1], b0v = bV[0], b1v = bV[1];
      short8 r8 = *(const short8*)(bs + 12288 + s*128 + j0*2);
      short8 k8 = *(const short8*)(bs + 14336 + s*128 + j0*2);
      float vi = b2f(*(const u16*)(bs + 16384 + s*128 + row*2));
      float yv = 0.f;
      #pragma unroll
      for (int e=0;e<4;++e){
        float Sq = S[e]*d0v[e] + sa*b0v[e] + vi*b2fs(k8[e]);
        S[e] = Sq;
        yv += Sq*b2fs(r8[e]);
      }
      #pragma unroll
      for (int e=0;e<4;++e){
        float Sq = S[4+e]*d1v[e] + sa*b1v[e] + vi*b2fs(k8[4+e]);
        S[4+e] = Sq;
        yv += Sq*b2fs(r8[4+e]);
      }
      ycur[s] = rdx8(yv);
    }
    #pragma unroll
    for (int s=0;s<RCH;++s) yprev[s] = ycur[s];
    cur = (cur+1==3)?0:cur+1;
  }
#undef RSTAGE
  {
    int t0 = (RNC-1)*RCH;
    #pragma unroll
    for (int s=0;s<RCH;++s) if (g==0) y[yb + (size_t)(t0+s)*CC] = f2b(yprev[s]);
  }
}

// ---------------- groupnorm + rk*v + gate -> z bf16
__global__ __launch_bounds__(256) void k_gn(
  const u16* __restrict__ y, const u16* __restrict__ rb, const u16* __restrict__ kb,
  const u16* __restrict__ vb, const float* __restrict__ r_k,
  const float* __restrict__ gnw, const float* __restrict__ gnb,
  const u16* __restrict__ gg, u16* __restrict__ z)
{
  int idx = blockIdx.x*4 + (threadIdx.x>>6);
  int l = threadIdx.x&63;
  int m = idx>>5, h = idx&31;
  int c = h*64 + l;
  size_t mo = (size_t)m*CC + c;
  float yv = b2f(y[mo]);
  float s = yv;
  #pragma unroll
  for (int o=32;o;o>>=1) s += __shfl_xor(s,o);
  float mean = s*(1.f/64.f);
  float dv = yv - mean;
  float vs = dv*dv;
  #pragma unroll
  for (int o=32;o;o>>=1) vs += __shfl_xor(vs,o);
  float gn = dv*rsqrtf(vs*(1.f/64.f) + 6.4e-4f)*gnw[c] + gnb[c];
  size_t ro = ((size_t)((m/TT)*HH + h)*TT + (m%TT))*64 + l;
  float rv=b2f(rb[ro]), kv=b2f(kb[ro]), vv=b2f(vb[ro]);
  float p = rv*kv*r_k[c];
  #pragma unroll
  for (int o=32;o;o>>=1) p += __shfl_xor(p,o);
  z[mo] = f2b((gn + p*vv)*b2f(gg[mo]));
}

extern "C" void kernel_launch(void* const* d_in, const int* in_sizes, int n_in,
                              void* d_out, int out_size, void* d_ws, size_t ws_size,
                              hipStream_t stream)
{
  (void)out_size;
  const float* x      = (const float*)d_in[0];
  const float* v_first= (const float*)d_in[1];
  const float* ln1_w  = (const float*)d_in[2];
  const float* ln1_b  = (const float*)d_in[3];
  const float* ln2_w  = (const float*)d_in[4];
  const float* ln2_b  = (const float*)d_in[5];
  const float* x_r    = (const float*)d_in[6];
  const float* x_w    = (const float*)d_in[7];
  const float* x_k    = (const float*)d_in[8];
  const float* x_v    = (const float*)d_in[9];
  const float* x_a    = (const float*)d_in[10];
  const float* x_g    = (const float*)d_in[11];
  const float* w0     = (const float*)d_in[12];
  const float* w1     = (const float*)d_in[13];
  const float* w2     = (const float*)d_in[14];
  const float* a0     = (const float*)d_in[15];
  const float* a1     = (const float*)d_in[16];
  const float* a2     = (const float*)d_in[17];
  const float* v0     = (const float*)d_in[18];
  const float* v1     = (const float*)d_in[19];
  const float* v2     = (const float*)d_in[20];
  const float* g1     = (const float*)d_in[21];
  const float* g2     = (const float*)d_in[22];
  const float* k_k    = (const float*)d_in[23];
  const float* k_a    = (const float*)d_in[24];
  const float* r_k    = (const float*)d_in[25];
  const float* W_r    = (const float*)d_in[26];
  const float* W_k    = (const float*)d_in[27];
  const float* W_v    = (const float*)d_in[28];
  const float* W_o    = (const float*)d_in[29];
  const float* gn_w   = (const float*)d_in[30];
  const float* gn_b   = (const float*)d_in[31];
  const float* ffn_x_k= (const float*)d_in[32];
  const float* W_key  = (const float*)d_in[33];
  const float* W_val  = (const float*)d_in[34];

  const size_t ME = (size_t)MM*CC;
  float* outF = (float*)d_out;

  bool ok = (n_in==35)
    && in_sizes[0]==6291456 && in_sizes[1]==6291456 && in_sizes[2]==2048
    && in_sizes[12]==2048 && in_sizes[13]==196608 && in_sizes[14]==196608
    && in_sizes[16]==196608 && in_sizes[19]==131072 && in_sizes[21]==524288
    && in_sizes[25]==2048 && in_sizes[26]==4194304 && in_sizes[33]==16777216
    && in_sizes[34]==16777216;
  if (!ok){
    k_fillf<<<2048, 256, 0, stream>>>(outF, 1099511627776.f, (int)ME);
    return;
  }

  constexpr size_t WS_NEED = 125829120 + 12582912;
  if (ws_size < WS_NEED){
    k_fillf<<<2048, 256, 0, stream>>>(outF, (float)(1u<<21) * (float)(ws_size>>20), (int)ME);
    return;
  }
  char* ws = (char*)d_ws;
  float* decay = (float*)(ws + 0);
  float* x1    = (float*)(ws + 0);
  u16* xn   = (u16*)(ws + 25165824);
  u16* WT   = (u16*)(ws + 25165824);
  float* bf32 = (float*)(ws + 25165824);
  u16* xw  = (u16*)(ws + 37748736);
  u16* xr  = (u16*)(ws + 37748736);
  u16* xn2 = (u16*)(ws + 37748736);
  float* af32 = (float*)(ws + 50331648);
  u16* xa  = (u16*)(ws + 50331648);
  u16* xk  = (u16*)(ws + 50331648);
  u16* xv  = (u16*)(ws + 62914560);
  u16* kf  = (u16*)(ws + 62914560);
  u16* xg  = (u16*)(ws + 75497472);
  u16* rsc = (u16*)(ws + 75497472);
  char* Fs = ws + 88080384;
  u16* B1T = (u16*)(Fs);
  u16* w2T = (u16*)(Fs + 2621440);
  u16* a2T = (u16*)(Fs + 3014656);
  u16* v2T = (u16*)(Fs + 3407872);
  u16* g2T = (u16*)(Fs + 3670016);
  u16* H1b = (u16*)(Fs + 4718592);
  u16* ksc = (u16*)(ws + 88080384);
  u16* asc = (u16*)(ws + 100663296);
  u16* ybuf= (u16*)(ws + 100663296);
  u16* gsc = (u16*)(ws + 113246208);
  u16* zbuf= (u16*)(ws + 113246208);
  u16* xcm = (u16*)(ws + 113246208);
  u16* WbigT = (u16*)(ws + 25165824);
  u16* outG = (u16*)(ws + 125829120);
  u16* vsc   = (u16*)d_out;
  u16* WrkvT = ((u16*)d_out) + ME;

  auto GEMM = [&](const u16* a0_, const u16* a1_, const u16* a2_,
                  int amode, int lda_, const u16* bt, int ldb_,
                  void* c0_, void* c1_, void* c2_, int ldc_,
                  int N_, int K_, int em, const float* aux_){
    k_gemm<<<dim3(N_/128, MM/128), 256, 0, stream>>>(a0_,a1_,a2_,amode,lda_,bt,ldb_,c0_,c1_,c2_,ldc_,K_,em,aux_);
  };
  auto GEMM2 = [&](const u16* a0_, const u16* a1_, const u16* a2_,
                   int amode, int lda_, const u16* bt, int ldb_,
                   void* c0_, void* c1_, void* c2_, int ldc_,
                   int N_, int K_, int em, const float* aux_){
    k_gemm2<<<dim3(N_/128, MM/256), 256, 0, stream>>>(a0_,a1_,a2_,amode,lda_,bt,ldb_,c0_,c1_,c2_,ldc_,K_,em,aux_);
  };
  dim3 tb(32,8);

  k_lnb<<<MM, 256, 0, stream>>>(x, ln1_w, ln1_b, xn);
  k_mixA<<<MM, 256, 0, stream>>>(xn, x_w, x_a, x_v, x_g, xw, xa, xv, xg);
  hipMemsetAsync(B1T, 0, 2621440, stream);
  k_tpose<<<dim3(3,64), tb, 0, stream>>>(w1, 2048,  96, B1T + 0*2048,   2048);
  k_tpose<<<dim3(3,64), tb, 0, stream>>>(a1, 2048,  96, B1T + 128*2048, 2048);
  k_tpose<<<dim3(2,64), tb, 0, stream>>>(v1, 2048,  64, B1T + 256*2048, 2048);
  k_tpose<<<dim3(8,64), tb, 0, stream>>>(g1, 2048, 256, B1T + 384*2048, 2048);
  k_tpose<<<dim3(64,3), tb, 0, stream>>>(w2,   96, 2048, w2T,  96);
  k_tpose<<<dim3(64,3), tb, 0, stream>>>(a2,   96, 2048, a2T,  96);
  k_tpose<<<dim3(64,2), tb, 0, stream>>>(v2,   64, 2048, v2T,  64);
  k_tpose<<<dim3(64,8), tb, 0, stream>>>(g2,  256, 2048, g2T, 256);
  GEMM(xw, xa, xv, 1, 2048, B1T, 2048, H1b, nullptr, nullptr, 640, 384, 2048, 7, nullptr);
  GEMM(xg, xg, xg, 0, 2048, B1T + 384*2048, 2048, H1b, nullptr, nullptr, 640, 256, 2048, 11, nullptr);
  GEMM(H1b + 0,   H1b, H1b, 0, 640, w2T,  96, decay, nullptr, nullptr, 2048, 2048,  96, 1, w0);
  GEMM(H1b + 128, H1b, H1b, 0, 640, a2T,  96, asc,   nullptr, nullptr, 2048, 2048,  96, 9, a0);
  GEMM(H1b + 256, H1b, H1b, 0, 640, v2T,  64, gsc,   nullptr, nullptr, 2048, 2048,  64, 9, v0);
  GEMM(H1b + 384, H1b, H1b, 0, 640, g2T, 256, outG,  nullptr, nullptr, 2048, 2048, 256, 6, nullptr);
  k_mixB<<<MM, 256, 0, stream>>>(xn, x_r, x_k, xr, xk);
  k_tpose<<<dim3(64,64), tb, 0, stream>>>(W_r, 2048, 2048, WrkvT,               2048);
  k_tpose<<<dim3(64,64), tb, 0, stream>>>(W_k, 2048, 2048, WrkvT + 2048*2048,   2048);
  k_tpose<<<dim3(64,64), tb, 0, stream>>>(W_v, 2048, 2048, WrkvT + 2*2048*2048, 2048);
  GEMM2(xr, xk, xv, 2, 2048, WrkvT, 2048, rsc, ksc, vsc, 2048, 6144, 2048, 10, nullptr);
  k_make_rec3<<<MM*HH/4, 256, 0, stream>>>(ksc, vsc, asc, gsc, af32, bf32, v_first, k_k, k_a);
  k_rwkv<<<256, 256, 0, stream>>>(decay, af32, bf32, rsc, ksc, vsc, ybuf);
  k_gn<<<MM*HH/4, 256, 0, stream>>>(ybuf, rsc, ksc, vsc, r_k, gn_w, gn_b, outG, zbuf);
  k_tpose<<<dim3(64,64), tb, 0, stream>>>(W_o, 2048, 2048, WT, 2048);
  GEMM(zbuf, zbuf, zbuf, 0, 2048, WT, 2048, x1, nullptr, nullptr, 2048, 2048, 2048, 3, x);
  k_lnb<<<MM, 256, 0, stream>>>(x1, ln2_w, ln2_b, xn2);
  k_mix1<<<MM, 256, 0, stream>>>(xn2, ffn_x_k, xcm);
  k_tpose<<<dim3(256,64), tb, 0, stream>>>(W_key, 2048, 8192, WbigT, 2048);
  GEMM2(xcm, xcm, xcm, 0, 2048, WbigT, 2048, kf, nullptr, nullptr, 8192, 8192, 2048, 4, nullptr);
  k_tpose<<<dim3(64,256), tb, 0, stream>>>(W_val, 8192, 2048, WbigT, 8192);
  GEMM(kf, kf, kf, 0, 8192, WbigT, 8192, outF, nullptr, nullptr, 2048, 2048, 8192, 3, x1);
  hipMemcpyAsync(outF + ME, v_first, ME*sizeof(float), hipMemcpyDeviceToDevice, stream);
}

// Round 20
// 1429.547 us; speedup vs baseline: 1.0745x; 1.0745x over previous
//
#include <hip/hip_runtime.h>
#include <stdint.h>

typedef unsigned short u16;
typedef __attribute__((ext_vector_type(8))) short short8;
typedef __attribute__((ext_vector_type(4))) float f32x4;

#define DEVI __device__ __forceinline__

static constexpr int TT = 768;
static constexpr int CC = 2048;
static constexpr int MM = 3072;
static constexpr int HH = 32;

DEVI float b2f(u16 u){ union{float f; unsigned int i;} x; x.i = ((unsigned int)u)<<16; return x.f; }
DEVI float b2fs(short s){ return b2f((u16)s); }
DEVI u16 f2b(float f){
  unsigned int u = __builtin_bit_cast(unsigned int, f);
  unsigned int r = (u + 0x7fffu + ((u>>16)&1u)) >> 16;
  return (u16)r;
}

DEVI void gload16(const void* g, void* s){
  __builtin_amdgcn_global_load_lds((const __attribute__((address_space(1))) void*)g,
                                   (__attribute__((address_space(3))) void*)s, 16, 0, 0);
}

// all-reduce over 8 consecutive lanes, pure DPP + half-mirror
DEVI float rdx8(float x){
  int xi = __builtin_bit_cast(int, x);
  x += __builtin_bit_cast(float, __builtin_amdgcn_update_dpp(0, xi, 0xB1, 0xF, 0xF, true));
  xi = __builtin_bit_cast(int, x);
  x += __builtin_bit_cast(float, __builtin_amdgcn_update_dpp(0, xi, 0x4E, 0xF, 0xF, true));
  xi = __builtin_bit_cast(int, x);
  x += __builtin_bit_cast(float, __builtin_amdgcn_update_dpp(0, xi, 0x141, 0xF, 0xF, true));
  return x;
}

__global__ __launch_bounds__(256) void k_fillf(float* __restrict__ out, float v, int n){
  for (int i = blockIdx.x*256 + threadIdx.x; i < n; i += gridDim.x*256) out[i] = v;
}

__global__ void k_tpose(const float* __restrict__ src, int R, int Cn, u16* __restrict__ dst, int ldd){
  __shared__ float tile[32][33];
  int c0 = blockIdx.x*32, r0 = blockIdx.y*32;
  #pragma unroll
  for (int i=0;i<4;++i){
    int r = r0 + threadIdx.y + i*8, c = c0 + threadIdx.x;
    tile[threadIdx.y + i*8][threadIdx.x] = (r<R && c<Cn) ? src[(size_t)r*Cn + c] : 0.f;
  }
  __syncthreads();
  #pragma unroll
  for (int i=0;i<4;++i){
    int c = c0 + threadIdx.y + i*8, r = r0 + threadIdx.x;
    if (c<Cn && r<R) dst[(size_t)c*ldd + r] = f2b(tile[threadIdx.x][threadIdx.y + i*8]);
  }
}

__global__ __launch_bounds__(256) void k_lnb(const float* __restrict__ in, const float* __restrict__ w,
                                             const float* __restrict__ bias, u16* __restrict__ out){
  __shared__ float red[8];
  int m = blockIdx.x;
  const float* x = in + (size_t)m*CC;
  float v[8]; float s=0.f, ss=0.f;
  #pragma unroll
  for (int i=0;i<8;++i){ v[i] = x[threadIdx.x + i*256]; s += v[i]; ss += v[i]*v[i]; }
  #pragma unroll
  for (int o=32;o;o>>=1){ s += __shfl_xor(s,o); ss += __shfl_xor(ss,o); }
  int wid = threadIdx.x>>6;
  if ((threadIdx.x&63)==0){ red[wid]=s; red[4+wid]=ss; }
  __syncthreads();
  s  = red[0]+red[1]+red[2]+red[3];
  ss = red[4]+red[5]+red[6]+red[7];
  float mean = s*(1.f/2048.f);
  float var  = ss*(1.f/2048.f) - mean*mean;
  float rstd = rsqrtf(fmaxf(var,0.f) + 1e-5f);
  #pragma unroll
  for (int i=0;i<8;++i){
    int c = threadIdx.x + i*256;
    out[(size_t)m*CC + c] = f2b((v[i]-mean)*rstd*w[c] + bias[c]);
  }
}

__global__ __launch_bounds__(256) void k_mixA(const u16* __restrict__ xn,
  const float* __restrict__ cw, const float* __restrict__ ca, const float* __restrict__ cv,
  const float* __restrict__ cg,
  u16* __restrict__ ow, u16* __restrict__ oa, u16* __restrict__ ov, u16* __restrict__ og)
{
  int m = blockIdx.x; int t = m % TT;
  const u16* cur = xn + (size_t)m*CC;
  const u16* prv = cur - CC;
  bool has = (t>0);
  #pragma unroll
  for (int i=0;i<8;++i){
    int c = threadIdx.x + i*256;
    float xc = b2f(cur[c]);
    float xx = (has ? b2f(prv[c]) : 0.f) - xc;
    size_t o = (size_t)m*CC + c;
    ow[o]=f2b(xc + xx*cw[c]); oa[o]=f2b(xc + xx*ca[c]);
    ov[o]=f2b(xc + xx*cv[c]); og[o]=f2b(xc + xx*cg[c]);
  }
}

__global__ __launch_bounds__(256) void k_mixB(const u16* __restrict__ xn,
  const float* __restrict__ cr, const float* __restrict__ ck,
  u16* __restrict__ orr, u16* __restrict__ ok)
{
  int m = blockIdx.x; int t = m % TT;
  const u16* cur = xn + (size_t)m*CC;
  const u16* prv = cur - CC;
  bool has = (t>0);
  #pragma unroll
  for (int i=0;i<8;++i){
    int c = threadIdx.x + i*256;
    float xc = b2f(cur[c]);
    float xx = (has ? b2f(prv[c]) : 0.f) - xc;
    size_t o = (size_t)m*CC + c;
    orr[o]=f2b(xc + xx*cr[c]); ok[o]=f2b(xc + xx*ck[c]);
  }
}

__global__ __launch_bounds__(256) void k_mix1(const u16* __restrict__ xn, const float* __restrict__ cf,
                                              u16* __restrict__ out){
  int m = blockIdx.x; int t = m % TT;
  const u16* cur = xn + (size_t)m*CC;
  const u16* prv = cur - CC;
  bool has = (t>0);
  #pragma unroll
  for (int i=0;i<8;++i){
    int c = threadIdx.x + i*256;
    float xc = b2f(cur[c]);
    float xx = (has ? b2f(prv[c]) : 0.f) - xc;
    out[(size_t)m*CC + c] = f2b(xc + xx*cf[c]);
  }
}

// ======== shared GEMM epilogue ========
#define GEMM_EPILOGUE(row, col, v) do{ \
        if (emode==0){ \
          ((float*)C0)[(size_t)(row)*ldc + (col)] = (v); \
        } else if (emode==1){ \
          float valw = aux[(col)] + (v); \
          float zneg = -valw; \
          float sp = (zneg > 20.f) ? zneg : log1pf(expf(zneg)); \
          float wlog = -sp - 0.5f; \
          float dec = expf(-expf(wlog)); \
          int b_ = (row)/TT, t_ = (row) - b_*TT; \
          int h_ = (col)>>6, n_ = (col)&63; \
          ((float*)C0)[((size_t)(b_*HH + h_)*TT + t_)*64 + n_] = dec; \
        } else if (emode==2){ \
          float s = 1.f/(1.f+expf(-(aux[(col)]+(v)))); \
          ((u16*)C0)[(size_t)(row)*ldc + (col)] = f2b(s); \
        } else if (emode==3){ \
          ((float*)C0)[(size_t)(row)*ldc + (col)] = aux[(size_t)(row)*ldc + (col)] + (v); \
        } else if (emode==4){ \
          float r_ = fmaxf((v), 0.f); \
          ((u16*)C0)[(size_t)(row)*ldc + (col)] = f2b(r_*r_); \
        } else if (emode==5){ \
          ((u16*)C0)[(size_t)(row)*ldc + (col)] = f2b(aux[(size_t)(row)*ldc + (col)] + (v)); \
        } else if (emode==6){ \
          ((u16*)C0)[(size_t)(row)*ldc + (col)] = f2b(v); \
        } else if (emode==7){ \
          float r_ = (v); \
          if ((col) < 128) r_ = tanhf(v); \
          else if ((col) >= 384) r_ = 1.f/(1.f+expf(-(v))); \
          ((u16*)C0)[(size_t)(row)*ldc + (col)] = f2b(r_); \
        } else if (emode==8){ \
          int b_ = (row)/TT, t_ = (row) - b_*TT; \
          int h_ = (col)>>6, n_ = (col)&63; \
          ((u16*)C0)[((size_t)(b_*HH + h_)*TT + t_)*64 + n_] = f2b(v); \
        } else if (emode==9){ \
          float s = 1.f/(1.f+expf(-(aux[(col)]+(v)))); \
          int b_ = (row)/TT, t_ = (row) - b_*TT; \
          int h_ = (col)>>6, n_ = (col)&63; \
          ((u16*)C0)[((size_t)(b_*HH + h_)*TT + t_)*64 + n_] = f2b(s); \
        } else if (emode==10){ \
          int g_ = (col)>>11, c2 = (col)&2047; \
          int b_ = (row)/TT, t_ = (row) - b_*TT; \
          int h_ = c2>>6, n_ = c2&63; \
          u16* dst = (g_==0)?(u16*)C0:(g_==1)?(u16*)C1:(u16*)C2; \
          dst[((size_t)(b_*HH + h_)*TT + t_)*64 + n_] = f2b(v); \
        } else { \
          float s = 1.f/(1.f+expf(-(v))); \
          ((u16*)C0)[(size_t)(row)*ldc + ((col)+384)] = f2b(s); \
        } \
  }while(0)

// ---------------- 128x128 GEMM (proven r13-r18): tri-buffered, counted vmcnt(4), XCD swizzle
__global__ __launch_bounds__(256,3) void k_gemm(
    const u16* A0, const u16* A1, const u16* A2,
    int amode, int lda,
    const u16* __restrict__ BT, int ldb,
    void* C0, void* C1, void* C2, int ldc, int K,
    int emode, const float* __restrict__ aux)
{
  const int tid = threadIdx.x;
  const int w = tid>>6, l = tid&63;

  const int NT = gridDim.x;
  const int nwg = NT * gridDim.y;
  int bid = blockIdx.y * NT + blockIdx.x;
  int qq = nwg >> 3, rr = nwg & 7;
  int xcd = bid & 7, pos = bid >> 3;
  int nid = (xcd < rr ? xcd*(qq+1) : rr*(qq+1) + (xcd-rr)*qq) + pos;
  const int ntile = nid % NT;
  const int mtile = nid / NT;

  const u16* A = A0;
  if (amode==1){ A = (ntile==0)?A0:(ntile==1)?A1:A2; }
  else if (amode==2){ int g = ntile>>4; A = (g==0)?A0:(g==1)?A1:A2; }

  __shared__ __align__(16) u16 As[3*4096];
  __shared__ __align__(16) u16 Bs[3*4096];

  const int sr = w*16 + (l>>2);
  const int sk = (((l&3) ^ ((l>>2)&3)))*8;
  const u16* Ag = A  + (size_t)(mtile*128 + sr)*lda + sk;
  const u16* Bg = BT + (size_t)(ntile*128 + sr)*ldb + sk;
  const size_t a64 = (size_t)64*lda, b64 = (size_t)64*ldb;
  const int wo = w*512;

  const int wm = w>>1, wn = w&1;
  const int fr = l&15;
  const int fq = ((l>>4) ^ (fr&3))*8;
  const int aoff = (wm*64 + fr)*32 + fq;
  const int boff = (wn*64 + fr)*32 + fq;

  f32x4 acc[4][4];
  const f32x4 zz = {0.f,0.f,0.f,0.f};
  #pragma unroll
  for (int mi=0;mi<4;++mi)
    #pragma unroll
    for (int ni=0;ni<4;++ni) acc[mi][ni] = zz;

  const int nt = K >> 5;

#define STAGE(bufi, k0) do{ \
    u16* dA = As + (bufi)*4096 + wo; \
    u16* dB = Bs + (bufi)*4096 + wo; \
    gload16(Ag + (k0),        dA); \
    gload16(Ag + a64 + (k0),  dA + 2048); \
    gload16(Bg + (k0),        dB); \
    gload16(Bg + b64 + (k0),  dB + 2048); \
  }while(0)

  STAGE(0, 0);
  if (nt > 1) STAGE(1, 32);

  int cur = 0;
  for (int t=0; t<nt; ++t){
    if (t == nt-1){ asm volatile("s_waitcnt vmcnt(0)" ::: "memory"); }
    else          { asm volatile("s_waitcnt vmcnt(4)" ::: "memory"); }
    __builtin_amdgcn_s_barrier();
    if (t+2 < nt){
      int nb = cur+2; if (nb>=3) nb-=3;
      STAGE(nb, (t+2)<<5);
    }
    const u16* Ab = As + cur*4096;
    const u16* Bb = Bs + cur*4096;
    short8 af[4], bfr[4];
    #pragma unroll
    for (int mi=0;mi<4;++mi) af[mi]  = *(const short8*)(Ab + aoff + mi*512);
    #pragma unroll
    for (int ni=0;ni<4;++ni) bfr[ni] = *(const short8*)(Bb + boff + ni*512);
    #pragma unroll
    for (int mi=0;mi<4;++mi)
      #pragma unroll
      for (int ni=0;ni<4;++ni)
        acc[mi][ni] = __builtin_amdgcn_mfma_f32_16x16x32_bf16(af[mi], bfr[ni], acc[mi][ni], 0,0,0);
    cur = (cur+1==3)?0:cur+1;
  }
#undef STAGE

  const int rb0 = mtile*128 + wm*64 + (l>>4)*4;
  const int cb0 = ntile*128 + wn*64 + fr;
  #pragma unroll
  for (int mi=0;mi<4;++mi){
    #pragma unroll
    for (int ni=0;ni<4;++ni){
      #pragma unroll
      for (int q2=0;q2<4;++q2){
        int row = rb0 + mi*16 + q2;
        int col = cb0 + ni*16;
        float v = acc[mi][ni][q2];
        GEMM_EPILOGUE(row, col, v);
      }
    }
  }
}

// ---------------- 64x128 GEMM for latency-bound small GEMMs: 4 waves of 64x32 (acc 4x2),
// LDS 36KB -> 4 blocks/CU, tri-buffered, counted vmcnt(3), XCD swizzle.
__global__ __launch_bounds__(256,4) void k_gemm3(
    const u16* A0, const u16* A1, const u16* A2,
    int amode, int lda,
    const u16* __restrict__ BT, int ldb,
    void* C0, void* C1, void* C2, int ldc, int K,
    int emode, const float* __restrict__ aux)
{
  const int tid = threadIdx.x;
  const int w = tid>>6, l = tid&63;

  const int NT = gridDim.x;
  const int nwg = NT * gridDim.y;
  int bid = blockIdx.y * NT + blockIdx.x;
  int qq = nwg >> 3, rr = nwg & 7;
  int xcd = bid & 7, pos = bid >> 3;
  int nid = (xcd < rr ? xcd*(qq+1) : rr*(qq+1) + (xcd-rr)*qq) + pos;
  const int ntile = nid % NT;
  const int mtile = nid / NT;

  const u16* A = A0;
  if (amode==1){ A = (ntile==0)?A0:(ntile==1)?A1:A2; }
  else if (amode==2){ int g = ntile>>4; A = (g==0)?A0:(g==1)?A1:A2; }

  __shared__ __align__(16) u16 As[3*2048];   // 64x32 per buffer
  __shared__ __align__(16) u16 Bs[3*4096];   // 128x32 per buffer

  const int srow = tid>>2;                    // 0..63
  const int skb = ((tid&3) ^ (srow&3))*8;     // pre-swizzled source col-block
  const u16* Ag = A  + (size_t)(mtile*64 + srow)*lda + skb;
  const u16* Bg = BT + (size_t)(ntile*128 + srow)*ldb + skb;
  const size_t b64 = (size_t)64*ldb;

  const int fr = l&15;
  const int fq = ((l>>4) ^ (fr&3))*8;
  const int aoff = fr*32 + fq;                // + mi*16*32
  const int boff = (w*32 + fr)*32 + fq;       // + ni*16*32

  f32x4 acc[4][2];
  const f32x4 zz = {0.f,0.f,0.f,0.f};
  #pragma unroll
  for (int mi=0;mi<4;++mi)
    #pragma unroll
    for (int ni=0;ni<2;++ni) acc[mi][ni] = zz;

  const int nt = K >> 5;

#define STAGE3(bufi, k0) do{ \
    gload16(Ag + (k0),        As + (bufi)*2048 + w*512); \
    gload16(Bg + (k0),        Bs + (bufi)*4096 + w*512); \
    gload16(Bg + b64 + (k0),  Bs + (bufi)*4096 + 2048 + w*512); \
  }while(0)

  STAGE3(0, 0);
  if (nt > 1) STAGE3(1, 32);

  int cur = 0;
  for (int t=0; t<nt; ++t){
    if (t == nt-1){ asm volatile("s_waitcnt vmcnt(0)" ::: "memory"); }
    else          { asm volatile("s_waitcnt vmcnt(3)" ::: "memory"); }
    __builtin_amdgcn_s_barrier();
    if (t+2 < nt){
      int nb = cur+2; if (nb>=3) nb-=3;
      STAGE3(nb, (t+2)<<5);
    }
    const u16* Ab = As + cur*2048;
    const u16* Bb = Bs + cur*4096;
    short8 af[4], bfr[2];
    #pragma unroll
    for (int mi=0;mi<4;++mi) af[mi]  = *(const short8*)(Ab + aoff + mi*512);
    #pragma unroll
    for (int ni=0;ni<2;++ni) bfr[ni] = *(const short8*)(Bb + boff + ni*512);
    #pragma unroll
    for (int mi=0;mi<4;++mi)
      #pragma unroll
      for (int ni=0;ni<2;++ni)
        acc[mi][ni] = __builtin_amdgcn_mfma_f32_16x16x32_bf16(af[mi], bfr[ni], acc[mi][ni], 0,0,0);
    cur = (cur+1==3)?0:cur+1;
  }
#undef STAGE3

  const int rb0 = mtile*64 + (l>>4)*4;
  const int cb0 = ntile*128 + w*32 + fr;
  #pragma unroll
  for (int mi=0;mi<4;++mi){
    #pragma unroll
    for (int ni=0;ni<2;++ni){
      #pragma unroll
      for (int q2=0;q2<4;++q2){
        int row = rb0 + mi*16 + q2;
        int col = cb0 + ni*16;
        float v = acc[mi][ni][q2];
        GEMM_EPILOGUE(row, col, v);
      }
    }
  }
}

// ---------------- rec prep: k,v in place; a,b to f32 buffers
__global__ __launch_bounds__(256) void k_make_rec3(
  u16* __restrict__ ksc, u16* __restrict__ vsc,
  const u16* __restrict__ asc, const u16* __restrict__ gsc,
  float* __restrict__ af, float* __restrict__ bf,
  const float* __restrict__ v_first, const float* __restrict__ k_k, const float* __restrict__ k_a)
{
  int idx = blockIdx.x*4 + (threadIdx.x>>6);
  int l = threadIdx.x & 63;
  int bh = idx / TT, t = idx - bh*TT;
  int b = bh >> 5, h = bh & 31;
  int c = h*64 + l;
  size_t off = (size_t)idx*64 + l;
  size_t mo = ((size_t)b*TT + t)*CC + c;
  float kq = b2f(ksc[off]);
  float vv = b2f(vsc[off]);
  float aa = b2f(asc[off]);
  float sg = b2f(gsc[off]);
  float vf = v_first[mo];
  float kkr = kq * k_k[c];
  float s2 = kkr*kkr;
  #pragma unroll
  for (int o=32;o;o>>=1) s2 += __shfl_xor(s2,o);
  float kk = kkr / fmaxf(sqrtf(s2), 1e-12f);
  ksc[off] = f2b(kq*(1.f + (aa-1.f)*k_a[c]));
  vsc[off] = f2b(vv + (vf-vv)*sg);
  af[off] = -kk;
  bf[off] = kk*aa;
}

// ---------------- RWKV7 recurrence (r17/r18 proven)
static constexpr int RCH = 16;
static constexpr int RNC = TT / RCH;
static constexpr int RBUF = 18432;

__global__ __launch_bounds__(256,1) void k_rwkv(
    const float* __restrict__ decay, const float* __restrict__ af, const float* __restrict__ bf,
    const u16* __restrict__ rb, const u16* __restrict__ kb, const u16* __restrict__ vb,
    u16* __restrict__ y)
{
  __shared__ __align__(16) char lds[3*RBUF];
  int blk = blockIdx.x;
  int bh = blk >> 1, half = blk & 1;
  int b = bh>>5, h = bh&31;
  int tid = threadIdx.x, w = tid>>6, l = tid&63;
  const int row = half*32 + w*8 + (l>>3);
  const int g = l&7;
  const int j0 = g*8;
  const size_t base = (size_t)bh * (TT*64);

  const float* dB = decay + base;
  const float* aB = af + base;
  const float* bB = bf + base;
  const u16*  rB = rb + base;
  const u16*  kB = kb + base;
  const u16*  vB = vb + base;

  float S[8];
  #pragma unroll
  for (int q=0;q<8;++q) S[q]=0.f;
  float ycur[RCH], yprev[RCH];
  size_t yb = (size_t)b*TT*CC + h*64 + row;

#define RSTAGE(bufi, c) do{ \
    char* bs = lds + (bufi)*RBUF; \
    size_t cf = (size_t)(c)*1024; \
    gload16(dB + cf + tid*4, bs + tid*16); \
    gload16(aB + cf + tid*4, bs + 4096 + tid*16); \
    gload16(bB + cf + tid*4, bs + 8192 + tid*16); \
    if (l < 32){ \
      int eo = w*256 + l*8; int bo = w*512 + l*16; \
      gload16(rB + cf + eo, bs + 12288 + bo); \
      gload16(kB + cf + eo, bs + 14336 + bo); \
      gload16(vB + cf + eo, bs + 16384 + bo); \
    } \
  }while(0)

  RSTAGE(0, 0);
  RSTAGE(1, 1);

  int cur = 0;
  for (int c=0; c<RNC; ++c){
    if (c == RNC-1){ asm volatile("s_waitcnt vmcnt(0)" ::: "memory"); }
    else           { asm volatile("s_waitcnt vmcnt(6)" ::: "memory"); }
    __builtin_amdgcn_s_barrier();
    if (c > 0){
      int t0 = (c-1)*RCH;
      #pragma unroll
      for (int s=0;s<RCH;++s) if (g==0) y[yb + (size_t)(t0+s)*CC] = f2b(yprev[s]);
    }
    asm volatile("" ::: "memory");
    if (c+2 < RNC){
      int nb = cur+2; if (nb>=3) nb-=3;
      RSTAGE(nb, c+2);
    }
    asm volatile("" ::: "memory");
    const char* bs = lds + cur*RBUF;
    #pragma unroll
    for (int s=0;s<RCH;++s){
      const f32x4* aV = (const f32x4*)(bs + 4096 + s*256 + j0*4);
      f32x4 a0v = aV[0], a1v = aV[1];
      float sa = ((S[0]*a0v[0] + S[1]*a0v[1]) + (S[2]*a0v[2] + S[3]*a0v[3]))
               + ((S[4]*a1v[0] + S[5]*a1v[1]) + (S[6]*a1v[2] + S[7]*a1v[3]));
      sa = rdx8(sa);
      const f32x4* dV = (const f32x4*)(bs + s*256 + j0*4);
      const f32x4* bV = (const f32x4*)(bs + 8192 + s*256 + j0*4);
      f32x4 d0v = dV[0], d1v = dV[1], b0v = bV[0], b1v = bV[1];
      short8 r8 = *(const short8*)(bs + 12288 + s*128 + j0*2);
      short8 k8 = *(const short8*)(bs + 14336 + s*128 + j0*2);
      float vi = b2f(*(const u16*)(bs + 16384 + s*128 + row*2));
      float yv = 0.f;
      #pragma unroll
      for (int e=0;e<4;++e){
        float Sq = S[e]*d0v[e] + sa*b0v[e] + vi*b2fs(k8[e]);
        S[e] = Sq;
        yv += Sq*b2fs(r8[e]);
      }
      #pragma unroll
      for (int e=0;e<4;++e){
        float Sq = S[4+e]*d1v[e] + sa*b1v[e] + vi*b2fs(k8[4+e]);
        S[4+e] = Sq;
        yv += Sq*b2fs(r8[4+e]);
      }
      ycur[s] = rdx8(yv);
    }
    #pragma unroll
    for (int s=0;s<RCH;++s) yprev[s] = ycur[s];
    cur = (cur+1==3)?0:cur+1;
  }
#undef RSTAGE
  {
    int t0 = (RNC-1)*RCH;
    #pragma unroll
    for (int s=0;s<RCH;++s) if (g==0) y[yb + (size_t)(t0+s)*CC] = f2b(yprev[s]);
  }
}

// ---------------- groupnorm + rk*v + gate -> z bf16
__global__ __launch_bounds__(256) void k_gn(
  const u16* __restrict__ y, const u16* __restrict__ rb, const u16* __restrict__ kb,
  const u16* __restrict__ vb, const float* __restrict__ r_k,
  const float* __restrict__ gnw, const float* __restrict__ gnb,
  const u16* __restrict__ gg, u16* __restrict__ z)
{
  int idx = blockIdx.x*4 + (threadIdx.x>>6);
  int l = threadIdx.x&63;
  int m = idx>>5, h = idx&31;
  int c = h*64 + l;
  size_t mo = (size_t)m*CC + c;
  float yv = b2f(y[mo]);
  float s = yv;
  #pragma unroll
  for (int o=32;o;o>>=1) s += __shfl_xor(s,o);
  float mean = s*(1.f/64.f);
  float dv = yv - mean;
  float vs = dv*dv;
  #pragma unroll
  for (int o=32;o;o>>=1) vs += __shfl_xor(vs,o);
  float gn = dv*rsqrtf(vs*(1.f/64.f) + 6.4e-4f)*gnw[c] + gnb[c];
  size_t ro = ((size_t)((m/TT)*HH + h)*TT + (m%TT))*64 + l;
  float rv=b2f(rb[ro]), kv=b2f(kb[ro]), vv=b2f(vb[ro]);
  float p = rv*kv*r_k[c];
  #pragma unroll
  for (int o=32;o;o>>=1) p += __shfl_xor(p,o);
  z[mo] = f2b((gn + p*vv)*b2f(gg[mo]));
}

extern "C" void kernel_launch(void* const* d_in, const int* in_sizes, int n_in,
                              void* d_out, int out_size, void* d_ws, size_t ws_size,
                              hipStream_t stream)
{
  (void)out_size;
  const float* x      = (const float*)d_in[0];
  const float* v_first= (const float*)d_in[1];
  const float* ln1_w  = (const float*)d_in[2];
  const float* ln1_b  = (const float*)d_in[3];
  const float* ln2_w  = (const float*)d_in[4];
  const float* ln2_b  = (const float*)d_in[5];
  const float* x_r    = (const float*)d_in[6];
  const float* x_w    = (const float*)d_in[7];
  const float* x_k    = (const float*)d_in[8];
  const float* x_v    = (const float*)d_in[9];
  const float* x_a    = (const float*)d_in[10];
  const float* x_g    = (const float*)d_in[11];
  const float* w0     = (const float*)d_in[12];
  const float* w1     = (const float*)d_in[13];
  const float* w2     = (const float*)d_in[14];
  const float* a0     = (const float*)d_in[15];
  const float* a1     = (const float*)d_in[16];
  const float* a2     = (const float*)d_in[17];
  const float* v0     = (const float*)d_in[18];
  const float* v1     = (const float*)d_in[19];
  const float* v2     = (const float*)d_in[20];
  const float* g1     = (const float*)d_in[21];
  const float* g2     = (const float*)d_in[22];
  const float* k_k    = (const float*)d_in[23];
  const float* k_a    = (const float*)d_in[24];
  const float* r_k    = (const float*)d_in[25];
  const float* W_r    = (const float*)d_in[26];
  const float* W_k    = (const float*)d_in[27];
  const float* W_v    = (const float*)d_in[28];
  const float* W_o    = (const float*)d_in[29];
  const float* gn_w   = (const float*)d_in[30];
  const float* gn_b   = (const float*)d_in[31];
  const float* ffn_x_k= (const float*)d_in[32];
  const float* W_key  = (const float*)d_in[33];
  const float* W_val  = (const float*)d_in[34];

  const size_t ME = (size_t)MM*CC;
  float* outF = (float*)d_out;

  bool ok = (n_in==35)
    && in_sizes[0]==6291456 && in_sizes[1]==6291456 && in_sizes[2]==2048
    && in_sizes[12]==2048 && in_sizes[13]==196608 && in_sizes[14]==196608
    && in_sizes[16]==196608 && in_sizes[19]==131072 && in_sizes[21]==524288
    && in_sizes[25]==2048 && in_sizes[26]==4194304 && in_sizes[33]==16777216
    && in_sizes[34]==16777216;
  if (!ok){
    k_fillf<<<2048, 256, 0, stream>>>(outF, 1099511627776.f, (int)ME);
    return;
  }

  constexpr size_t WS_NEED = 125829120 + 12582912;
  if (ws_size < WS_NEED){
    k_fillf<<<2048, 256, 0, stream>>>(outF, (float)(1u<<21) * (float)(ws_size>>20), (int)ME);
    return;
  }
  char* ws = (char*)d_ws;
  float* decay = (float*)(ws + 0);
  float* x1    = (float*)(ws + 0);
  u16* xn   = (u16*)(ws + 25165824);
  u16* WT   = (u16*)(ws + 25165824);
  float* bf32 = (float*)(ws + 25165824);
  u16* xw  = (u16*)(ws + 37748736);
  u16* xr  = (u16*)(ws + 37748736);
  u16* xn2 = (u16*)(ws + 37748736);
  float* af32 = (float*)(ws + 50331648);
  u16* xa  = (u16*)(ws + 50331648);
  u16* xk  = (u16*)(ws + 50331648);
  u16* xv  = (u16*)(ws + 62914560);
  u16* kf  = (u16*)(ws + 62914560);
  u16* xg  = (u16*)(ws + 75497472);
  u16* rsc = (u16*)(ws + 75497472);
  char* Fs = ws + 88080384;
  u16* B1T = (u16*)(Fs);
  u16* w2T = (u16*)(Fs + 2621440);
  u16* a2T = (u16*)(Fs + 3014656);
  u16* v2T = (u16*)(Fs + 3407872);
  u16* g2T = (u16*)(Fs + 3670016);
  u16* H1b = (u16*)(Fs + 4718592);
  u16* ksc = (u16*)(ws + 88080384);
  u16* asc = (u16*)(ws + 100663296);
  u16* ybuf= (u16*)(ws + 100663296);
  u16* gsc = (u16*)(ws + 113246208);
  u16* zbuf= (u16*)(ws + 113246208);
  u16* xcm = (u16*)(ws + 113246208);
  u16* WbigT = (u16*)(ws + 25165824);
  u16* outG = (u16*)(ws + 125829120);
  u16* vsc   = (u16*)d_out;
  u16* WrkvT = ((u16*)d_out) + ME;

  auto GEMM = [&](const u16* a0_, const u16* a1_, const u16* a2_,
                  int amode, int lda_, const u16* bt, int ldb_,
                  void* c0_, void* c1_, void* c2_, int ldc_,
                  int N_, int K_, int em, const float* aux_){
    k_gemm<<<dim3(N_/128, MM/128), 256, 0, stream>>>(a0_,a1_,a2_,amode,lda_,bt,ldb_,c0_,c1_,c2_,ldc_,K_,em,aux_);
  };
  auto GEMM3 = [&](const u16* a0_, const u16* a1_, const u16* a2_,
                   int amode, int lda_, const u16* bt, int ldb_,
                   void* c0_, void* c1_, void* c2_, int ldc_,
                   int N_, int K_, int em, const float* aux_){
    k_gemm3<<<dim3(N_/128, MM/64), 256, 0, stream>>>(a0_,a1_,a2_,amode,lda_,bt,ldb_,c0_,c1_,c2_,ldc_,K_,em,aux_);
  };
  dim3 tb(32,8);

  k_lnb<<<MM, 256, 0, stream>>>(x, ln1_w, ln1_b, xn);
  k_mixA<<<MM, 256, 0, stream>>>(xn, x_w, x_a, x_v, x_g, xw, xa, xv, xg);
  hipMemsetAsync(B1T, 0, 2621440, stream);
  k_tpose<<<dim3(3,64), tb, 0, stream>>>(w1, 2048,  96, B1T + 0*2048,   2048);
  k_tpose<<<dim3(3,64), tb, 0, stream>>>(a1, 2048,  96, B1T + 128*2048, 2048);
  k_tpose<<<dim3(2,64), tb, 0, stream>>>(v1, 2048,  64, B1T + 256*2048, 2048);
  k_tpose<<<dim3(8,64), tb, 0, stream>>>(g1, 2048, 256, B1T + 384*2048, 2048);
  k_tpose<<<dim3(64,3), tb, 0, stream>>>(w2,   96, 2048, w2T,  96);
  k_tpose<<<dim3(64,3), tb, 0, stream>>>(a2,   96, 2048, a2T,  96);
  k_tpose<<<dim3(64,2), tb, 0, stream>>>(v2,   64, 2048, v2T,  64);
  k_tpose<<<dim3(64,8), tb, 0, stream>>>(g2,  256, 2048, g2T, 256);
  GEMM3(xw, xa, xv, 1, 2048, B1T, 2048, H1b, nullptr, nullptr, 640, 384, 2048, 7, nullptr);
  GEMM3(xg, xg, xg, 0, 2048, B1T + 384*2048, 2048, H1b, nullptr, nullptr, 640, 256, 2048, 11, nullptr);
  GEMM3(H1b + 0,   H1b, H1b, 0, 640, w2T,  96, decay, nullptr, nullptr, 2048, 2048,  96, 1, w0);
  GEMM3(H1b + 128, H1b, H1b, 0, 640, a2T,  96, asc,   nullptr, nullptr, 2048, 2048,  96, 9, a0);
  GEMM3(H1b + 256, H1b, H1b, 0, 640, v2T,  64, gsc,   nullptr, nullptr, 2048, 2048,  64, 9, v0);
  GEMM3(H1b + 384, H1b, H1b, 0, 640, g2T, 256, outG,  nullptr, nullptr, 2048, 2048, 256, 6, nullptr);
  k_mixB<<<MM, 256, 0, stream>>>(xn, x_r, x_k, xr, xk);
  k_tpose<<<dim3(64,64), tb, 0, stream>>>(W_r, 2048, 2048, WrkvT,               2048);
  k_tpose<<<dim3(64,64), tb, 0, stream>>>(W_k, 2048, 2048, WrkvT + 2048*2048,   2048);
  k_tpose<<<dim3(64,64), tb, 0, stream>>>(W_v, 2048, 2048, WrkvT + 2*2048*2048, 2048);
  GEMM(xr, xk, xv, 2, 2048, WrkvT, 2048, rsc, ksc, vsc, 2048, 6144, 2048, 10, nullptr);
  k_make_rec3<<<MM*HH/4, 256, 0, stream>>>(ksc, vsc, asc, gsc, af32, bf32, v_first, k_k, k_a);
  k_rwkv<<<256, 256, 0, stream>>>(decay, af32, bf32, rsc, ksc, vsc, ybuf);
  k_gn<<<MM*HH/4, 256, 0, stream>>>(ybuf, rsc, ksc, vsc, r_k, gn_w, gn_b, outG, zbuf);
  k_tpose<<<dim3(64,64), tb, 0, stream>>>(W_o, 2048, 2048, WT, 2048);
  GEMM3(zbuf, zbuf, zbuf, 0, 2048, WT, 2048, x1, nullptr, nullptr, 2048, 2048, 2048, 3, x);
  k_lnb<<<MM, 256, 0, stream>>>(x1, ln2_w, ln2_b, xn2);
  k_mix1<<<MM, 256, 0, stream>>>(xn2, ffn_x_k, xcm);
  k_tpose<<<dim3(256,64), tb, 0, stream>>>(W_key, 2048, 8192, WbigT, 2048);
  GEMM(xcm, xcm, xcm, 0, 2048, WbigT, 2048, kf, nullptr, nullptr, 8192, 8192, 2048, 4, nullptr);
  k_tpose<<<dim3(64,256), tb, 0, stream>>>(W_val, 8192, 2048, WbigT, 8192);
  GEMM(kf, kf, kf, 0, 8192, WbigT, 8192, outF, nullptr, nullptr, 2048, 2048, 8192, 3, x1);
  hipMemcpyAsync(outF + ME, v_first, ME*sizeof(float), hipMemcpyDeviceToDevice, stream);
}